// Round 10
// baseline (253.400 us; speedup 1.0000x reference)
//
#include <hip/hip_runtime.h>

#define N_TOK 4096
#define DIM   1024

typedef __bf16 bf16x8 __attribute__((ext_vector_type(8)));
typedef float  f32x4  __attribute__((ext_vector_type(4)));

__device__ __forceinline__ unsigned short f2bf(float f) {
  union { float f; unsigned u; } v; v.f = f;
  unsigned u = v.u;
  return (unsigned short)((u + 0x7fffu + ((u >> 16) & 1u)) >> 16);
}
__device__ __forceinline__ float bf2f(unsigned short h) {
  union { unsigned u; float f; } v; v.u = ((unsigned)h) << 16;
  return v.f;
}

// async global->LDS, 16 B/lane: lane's data lands at (uniform lds base) + lane*16
__device__ __forceinline__ void gll16(const unsigned short* g,
                                      unsigned short* l) {
  __builtin_amdgcn_global_load_lds(
      (const __attribute__((address_space(1))) unsigned int*)g,
      (__attribute__((address_space(3))) unsigned int*)l, 16, 0, 0);
}

// ---------------------------------------------------------------------------
// Fused prep kernel (round-9 proven) — all independent pre-GEMM work:
//   job CVT  [0,2048):     xb = bf16(x), 8 elems/thread
//   job TQ/TK/TV (+1024):  Wt[n][k] = bf16(W[k][n]) via 32x32 LDS tile
//   job ZERO [5120,5888):  out rows 1024..4096 = 0 (exact: 768*256*4 float4)
//   job LSUM [5888,5892):  Lsum = 0
//   job BIAS [5892,5895):  ball = {bq/32, bk, bv}
// ---------------------------------------------------------------------------
#define PB_CVT 0
#define PB_TQ 2048
#define PB_ZERO 5120
#define PB_LSUM 5888
#define PB_BIAS 5892
#define PB_TOTAL 5895

__global__ void prep(const float* __restrict__ x, const float* __restrict__ Wq,
                     const float* __restrict__ Wk, const float* __restrict__ Wv,
                     const float* __restrict__ bq, const float* __restrict__ bk,
                     const float* __restrict__ bv,
                     unsigned short* __restrict__ xb,
                     unsigned short* __restrict__ Wt,
                     float* __restrict__ out, float* __restrict__ ball,
                     float* __restrict__ Lsum) {
  const int b = blockIdx.x;
  const int t = threadIdx.x;
  if (b < PB_TQ) {  // CVT
    const int i = ((b - PB_CVT) * 256 + t) * 8;
    float4 v0 = *(const float4*)(x + i);
    float4 v1 = *(const float4*)(x + i + 4);
    ushort4 r0, r1;
    r0.x = f2bf(v0.x); r0.y = f2bf(v0.y); r0.z = f2bf(v0.z); r0.w = f2bf(v0.w);
    r1.x = f2bf(v1.x); r1.y = f2bf(v1.y); r1.z = f2bf(v1.z); r1.w = f2bf(v1.w);
    *(ushort4*)(xb + i) = r0;
    *(ushort4*)(xb + i + 4) = r1;
  } else if (b < PB_ZERO) {  // transpose one 32x32 tile of one W
    const int which = (b - PB_TQ) >> 10;          // 0,1,2
    const int lb = (b - PB_TQ) & 1023;
    const float* W = (which == 0) ? Wq : (which == 1) ? Wk : Wv;
    unsigned short* D = Wt + (size_t)which * 1024 * 1024;
    __shared__ float tile[32][33];
    const int bx = (lb & 31) * 32, by = (lb >> 5) * 32;
    const int tx = t & 31, ty = t >> 5;  // ty in 0..7
    for (int r = ty; r < 32; r += 8)
      tile[r][tx] = W[(size_t)(by + r) * DIM + bx + tx];
    __syncthreads();
    for (int r = ty; r < 32; r += 8)
      D[(size_t)(bx + r) * DIM + by + tx] = f2bf(tile[tx][r]);
  } else if (b < PB_LSUM) {  // zero out rows >= 1024 (3M floats)
    float4* p = (float4*)(out + (size_t)1024 * DIM);
    const int i = ((b - PB_ZERO) * 256 + t) * 4;
#pragma unroll
    for (int c = 0; c < 4; c++) p[i + c] = make_float4(0.f, 0.f, 0.f, 0.f);
  } else if (b < PB_BIAS) {  // Lsum zero
    const int i = ((b - PB_LSUM) * 256 + t) * 4;
    *(float4*)(Lsum + i) = make_float4(0.f, 0.f, 0.f, 0.f);
  } else {  // bias, 4/thread
    const int i = ((b - PB_BIAS) * 256 + t) * 4;
#pragma unroll
    for (int c = 0; c < 4; c++) {
      const int k = i + c;
      if (k < 3072)
        ball[k] = (k < 1024) ? bq[k] * 0.03125f
                             : ((k < 2048) ? bk[k - 1024] : bv[k - 2048]);
    }
  }
}

// ---------------------------------------------------------------------------
// bf16 transpose: Vt[n][m] = V[m][n]  (V = Call's V columns)
// ---------------------------------------------------------------------------
__global__ void transpose_bf16(const unsigned short* __restrict__ V, int ldv,
                               unsigned short* __restrict__ Vt, int ldvt) {
  __shared__ unsigned short tile[32][33];
  int bx = blockIdx.x * 32;  // n
  int by = blockIdx.y * 32;  // m
  int tx = threadIdx.x, ty = threadIdx.y;
  for (int r = ty; r < 32; r += 8)
    tile[r][tx] = V[(size_t)(by + r) * ldv + bx + tx];
  __syncthreads();
  for (int r = ty; r < 32; r += 8)
    Vt[(size_t)(bx + r) * ldvt + by + tx] = tile[tx][r];
}

// ---------------------------------------------------------------------------
// A·B^T MFMA GEMM — 64x128 tile (was 128x128): ~2x blocks/CU for latency
// cover (round-9 counters: MfmaUtil 11%, occupancy 18%, nothing near a
// ceiling -> latency-starved at 2-2.5 blocks/CU). 4 waves, each 32x64
// (acc[2][4]). BK=64, gll16 staging, contiguous LDS (m97 layout), 24 KB.
// bm indexes 64-ROW blocks everywhere.
// EPI 0: concat QKV projection. bf16 store, acc*colscale + ball[gc].
// EPI 2: U = exp(score) causal (col>row -> 0), bf16 store; skip blocks
//        fully above diagonal (2*bn > bm); row sums -> atomicAdd Lsum.
// EPI 3: O = (U V)/L[row]. split-K over blockIdx.z (1024 chunks clipped to
//        Keff=(bm+1)*64); direct store if single chunk else atomicAdd.
// ---------------------------------------------------------------------------
#define BK 64

template <int EPI>
__global__ void gemm_tn(const unsigned short* __restrict__ A,
                        const unsigned short* __restrict__ B,
                        void* __restrict__ Cout,
                        const float* __restrict__ bias,
                        float* __restrict__ Lsum,
                        int K, int lda, int ldb, int ldc) {
  int bm, bn, kbeg, kend;
  bool single = true;
  if (EPI == 3) {
    bn = blockIdx.x; bm = blockIdx.y;
    const int Keff = (bm + 1) * 64;
    kbeg = blockIdx.z * 1024;
    if (kbeg >= Keff) return;
    kend = min(kbeg + 1024, Keff);
    single = (Keff <= 1024);
  } else {
    bm = blockIdx.y; bn = blockIdx.x;
    if (EPI == 2 && 2 * bn > bm) return;
    kbeg = 0; kend = K;
  }

  __shared__ __align__(16) unsigned short smA[64 * 64];   // 8 KB
  __shared__ __align__(16) unsigned short smB[128 * 64];  // 16 KB

  const int t = threadIdx.x;
  const int lane = t & 63, w = t >> 6;
  const int wm = (w & 1) * 32, wn = (w >> 1) * 64;

  f32x4 acc[2][4] = {};

  const unsigned short* Ab = A + (size_t)bm * 64 * lda;
  const unsigned short* Bb = B + (size_t)bn * 128 * ldb;

  const int rA = wm + (lane & 15);
  const int rB = wn + (lane & 15);
  const int kquad = (lane >> 4) << 3;

  // staging source: row lr = lane>>3, k-chunk (lane&7)*8
  const int lr = lane >> 3;
  const int g8 = (lane & 7) << 3;
  const unsigned short* pa = Ab + (size_t)lr * lda + g8 + kbeg;
  const unsigned short* pb = Bb + (size_t)lr * ldb + g8 + kbeg;

  for (int k0 = kbeg; k0 < kend; k0 += BK) {
    __syncthreads();
    // A: 64 rows -> wave w stages rows w*16 + {0,8}
#pragma unroll
    for (int m = 0; m < 2; m++) {
      const int r0 = (w << 4) + (m << 3);
      gll16(pa + (size_t)r0 * lda, smA + r0 * 64);
    }
    // B: 128 rows -> wave w stages rows w*32 + {0,8,16,24}
#pragma unroll
    for (int m = 0; m < 4; m++) {
      const int r0 = (w << 5) + (m << 3);
      gll16(pb + (size_t)r0 * ldb, smB + r0 * 64);
    }
    pa += BK; pb += BK;
    __syncthreads();  // drains vmcnt -> tiles resident

#pragma unroll
    for (int kk = 0; kk < BK; kk += 32) {
      bf16x8 af[2], bfr[4];
      const int kof = kk + kquad;
#pragma unroll
      for (int i = 0; i < 2; i++)
        af[i] = *(const bf16x8*)(&smA[(rA + i * 16) * 64 + kof]);
#pragma unroll
      for (int j = 0; j < 4; j++)
        bfr[j] = *(const bf16x8*)(&smB[(rB + j * 16) * 64 + kof]);
#pragma unroll
      for (int i = 0; i < 2; i++)
#pragma unroll
        for (int j = 0; j < 4; j++)
          acc[i][j] = __builtin_amdgcn_mfma_f32_16x16x32_bf16(af[i], bfr[j],
                                                              acc[i][j], 0, 0, 0);
    }
  }

  // Epilogues. C/D layout: col = lane&15, row = (lane>>4)*4 + reg.
  float* Cf = (float*)Cout;
  unsigned short* Ch = (unsigned short*)Cout;
  const int colbase = bn * 128 + wn + (lane & 15);
  const int rowbase = bm * 64 + wm + ((lane >> 4) << 2);

  if (EPI == 0) {
#pragma unroll
    for (int i = 0; i < 2; i++)
#pragma unroll
      for (int j = 0; j < 4; j++) {
        const int gc = colbase + j * 16;
        const float cs = (gc < 1024) ? 0.03125f : 1.0f;
#pragma unroll
        for (int r = 0; r < 4; r++) {
          const int gr = rowbase + i * 16 + r;
          Ch[(size_t)gr * ldc + gc] = f2bf(acc[i][j][r] * cs + bias[gc]);
        }
      }
  } else if (EPI == 2) {
    // U = exp(score), causal; block row-sum (64 rows) -> atomicAdd Lsum.
    __syncthreads();                 // all LDS reads done; repurpose smA
    float* Lp = (float*)smA;         // 64 floats
    if (t < 64) Lp[t] = 0.f;
    __syncthreads();
#pragma unroll
    for (int i = 0; i < 2; i++)
#pragma unroll
      for (int r = 0; r < 4; r++) {
        const int gr = rowbase + i * 16 + r;
        float sj = 0.f;
#pragma unroll
        for (int j = 0; j < 4; j++) {
          const int gc = colbase + j * 16;
          unsigned short h = 0;
          if (gc <= gr) h = f2bf(__expf(acc[i][j][r]));
          Ch[(size_t)gr * ldc + gc] = h;
          sj += bf2f(h);  // sum the rounded value so L matches stored U
        }
        sj += __shfl_xor(sj, 1);
        sj += __shfl_xor(sj, 2);
        sj += __shfl_xor(sj, 4);
        sj += __shfl_xor(sj, 8);
        if ((lane & 15) == 0)
          atomicAdd(&Lp[wm + ((lane >> 4) << 2) + i * 16 + r], sj);
      }
    __syncthreads();
    if (t < 64) atomicAdd(&Lsum[bm * 64 + t], Lp[t]);
  } else {
#pragma unroll
    for (int i = 0; i < 2; i++)
#pragma unroll
      for (int r = 0; r < 4; r++) {
        const int gr = rowbase + i * 16 + r;
        const float linv = 1.0f / Lsum[gr];
#pragma unroll
        for (int j = 0; j < 4; j++) {
          const int gc = colbase + j * 16;
          const float v = acc[i][j][r] * linv;
          if (single)
            Cf[(size_t)gr * ldc + gc] = v;
          else
            atomicAdd(&Cf[(size_t)gr * ldc + gc], v);
        }
      }
  }
}

// ---------------------------------------------------------------------------
// kernel_launch — 5 launches.  ws layout (ushort elems):
//   [0,4M)    xb [4096x1024]; after concat GEMM, reused as V^T [1024x4096]
//   [4M,7M)   W_all^T = Wq^T | Wk^T | Wv^T  (3072 x 1024)
//   [7M,19M)  Call [4096x3072] = Q | K | V  (Q pre-scaled by 1/32)
//   [19M,35M) Sb [4096x4096]  (U = exp scores)
//   [35M,..)  ball [3072] f32, Lsum [4096] f32
// ---------------------------------------------------------------------------
extern "C" void kernel_launch(void* const* d_in, const int* in_sizes, int n_in,
                              void* d_out, int out_size, void* d_ws,
                              size_t ws_size, hipStream_t stream) {
  (void)in_sizes; (void)n_in; (void)out_size; (void)ws_size;
  const float* x  = (const float*)d_in[0];
  const float* Wq = (const float*)d_in[1];
  const float* bq = (const float*)d_in[2];
  const float* Wk = (const float*)d_in[3];
  const float* bk = (const float*)d_in[4];
  const float* Wv = (const float*)d_in[5];
  const float* bv = (const float*)d_in[6];
  float* out = (float*)d_out;

  const size_t M1 = (size_t)1024 * 1024;
  unsigned short* xb   = (unsigned short*)d_ws;   // 4M elems; later V^T
  unsigned short* Wt   = xb + 4 * M1;             // 3M elems
  unsigned short* Call = Wt + 3 * M1;             // 12M elems
  unsigned short* Sb   = Call + 12 * M1;          // 16M elems
  float* ball          = (float*)(Sb + 16 * M1);  // 3072 f32
  float* Lsum          = ball + 3072;             // 4096 f32

  // 1) all prep in one launch
  prep<<<PB_TOTAL, 256, 0, stream>>>(x, Wq, Wk, Wv, bq, bk, bv, xb, Wt, out,
                                     ball, Lsum);
  // 2) Call = x @ [Wq|Wk|Wv] + ball. 1536 blocks (6/CU).
  gemm_tn<0><<<dim3(24, 64), 256, 0, stream>>>(xb, Wt, Call, ball, nullptr,
                                               DIM, DIM, DIM, 3 * DIM);
  // 3) V^T into the dead xb slot.
  transpose_bf16<<<dim3(32, 128), dim3(32, 8), 0, stream>>>(Call + 2048,
                                                            3 * DIM, xb, N_TOK);
  // 4) U = exp(Q K^T) causal + row sums Lsum. 1056 active blocks (4.1/CU).
  gemm_tn<2><<<dim3(32, 64), 256, 0, stream>>>(Call, Call + 1024, Sb, nullptr,
                                               Lsum, DIM, 3 * DIM, 3 * DIM,
                                               N_TOK);
  // 5) O = (U V) / L, split-K over z (4 chunks of 1024). 1280 active (5/CU).
  gemm_tn<3><<<dim3(8, 64, 4), 256, 0, stream>>>(Sb, xb, out, nullptr, Lsum,
                                                 N_TOK, N_TOK, N_TOK, DIM);
}